// Round 18
// baseline (791.881 us; speedup 1.0000x reference)
//
#include <hip/hip_runtime.h>
#include <hip/hip_fp16.h>

#define CDIM 512
#define ROWS 65536
#define NSTEPS 16     // K-steps of 32

typedef _Float16 half8  __attribute__((ext_vector_type(8)));
typedef __fp16   fp16x2 __attribute__((ext_vector_type(2)));
typedef float    f32x16 __attribute__((ext_vector_type(16)));

// async global->LDS, 16B per lane; LDS dest = wave-uniform base + lane*16
#define GLD_LDS16(gp, lp) __builtin_amdgcn_global_load_lds( \
    (const __attribute__((address_space(1))) unsigned int*)(gp), \
    (__attribute__((address_space(3))) unsigned int*)(lp), 16, 0, 0)

__device__ __forceinline__ half8 cvt8(float4 f0, float4 f1) {
    union { fp16x2 h2[4]; half8 h8; } u;
    u.h2[0] = __builtin_amdgcn_cvt_pkrtz(f0.x, f0.y);
    u.h2[1] = __builtin_amdgcn_cvt_pkrtz(f0.z, f0.w);
    u.h2[2] = __builtin_amdgcn_cvt_pkrtz(f1.x, f1.y);
    u.h2[3] = __builtin_amdgcn_cvt_pkrtz(f1.z, f1.w);
    return u.h8;
}

// ---------------- K1 (fused): blocks 0..31 qproj, blocks 32..159 wkfrag ----------------
__global__ void prep_kernel(const float* __restrict__ Q, const float* __restrict__ Wq,
                            const float* __restrict__ bq, const float* __restrict__ Wout,
                            const float* __restrict__ Wk,
                            float* __restrict__ v, _Float16* __restrict__ Wkf) {
    __shared__ float qs[CDIM];
    const int t = threadIdx.x;
    if (blockIdx.x < 32) {
        // v[j] = relu(Q.Wq[j,:]+bq[j]) * Wout[j/64] / 8 ; bout dropped (softmax shift-invariant)
        qs[t] = Q[t]; qs[t + 256] = Q[t + 256];
        __syncthreads();
        const int jj  = t >> 4;
        const int sub = t & 15;
        const int j   = blockIdx.x * 16 + jj;
        const float4* w4 = (const float4*)(Wq + (size_t)j * CDIM + sub * 32);
        const float4* q4 = (const float4*)(qs + sub * 32);
        float s = 0.f;
        #pragma unroll
        for (int i = 0; i < 8; ++i) {
            float4 w = w4[i]; float4 q = q4[i];
            s = fmaf(w.x, q.x, s); s = fmaf(w.y, q.y, s);
            s = fmaf(w.z, q.z, s); s = fmaf(w.w, q.w, s);
        }
        s += __shfl_xor(s, 1); s += __shfl_xor(s, 2);
        s += __shfl_xor(s, 4); s += __shfl_xor(s, 8);
        if (sub == 0) {
            s += bq[j];
            s = fmaxf(s, 0.f);
            v[j] = s * Wout[j >> 6] * 0.125f;
        }
    } else {
        // Wk -> fp16 B-fragments [jb 0..15][kc 0..31][lane 0..63][8 halfs]
        // frag(jb,kc) lane l: B[k=kc*16+(l>>5)*8+e][j=jb*32+(l&31)]
        const int gid = (blockIdx.x - 32) * 256 + t;
        const int jb  = gid >> 11;
        const int kc  = (gid >> 6) & 31;
        const int l   = gid & 63;
        const int j   = jb * 32 + (l & 31);
        const int k   = kc * 16 + (l >> 5) * 8;
        const float* src = Wk + (size_t)j * CDIM + k;
        float4 f0 = *(const float4*)(src);
        float4 f1 = *(const float4*)(src + 4);
        *(half8*)(Wkf + (size_t)gid * 8) = cvt8(f0, f1);
    }
}

// ---------------- K2: no-class GEMM 128 rows x ALL 512 j x K-step 32 --------------------
// 512 WGs x 512 thr (8 waves: wm 2 x wn 4; per wave 64 rows x 128 j, acc[2][4]).
// Each K row read by exactly ONE WG -> logical K traffic = 134MB (fits L3 across replays).
// LDS 80KB exactly (A dbuf 16KB + B dbuf 64KB) -> 2 WGs/CU; scr aliased onto dead Ab.
// A: coalesced reg-stage (1 row-chunk/thread) -> frag-major LDS. B: 4 GLD_LDS16/wave/step.
__global__ __launch_bounds__(512, 4) void score_kernel(
    const float* __restrict__ Kmat, const _Float16* __restrict__ Wkf,
    const float* __restrict__ bk, const float* __restrict__ v,
    float* __restrict__ logits)
{
    __shared__ alignas(16) char lds[81920];   // Ab[2][8192] @0 ; Bb[2][32768] @16384
    char* const Ab = lds;
    char* const Bb = lds + 16384;

    const int tid  = threadIdx.x;
    const int lane = tid & 63;
    const int wave = tid >> 6;          // 0..7
    const int l31  = lane & 31;
    const int lhi  = lane >> 5;
    const int wm   = wave >> 2;         // 0..1
    const int wn   = wave & 3;          // 0..3
    const int rowbase = blockIdx.x * 128;

    // A staging (coalesced): thread -> row sr (0..127), 8-float chunk sc (0..3)
    const int sr = tid >> 2;
    const int sc = tid & 3;
    const float* gA = Kmat + (size_t)(rowbase + sr) * CDIM + sc * 8;
    const int adst = (((sr >> 5) * 2 + (sc >> 1)) << 10) + (((sr & 31) + ((sc & 1) << 5)) << 4);
    // B staging: wave stages jb in {2w, 2w+1} x kcl in {0,1}
    const char* gB = (const char*)Wkf;

    f32x16 acc[2][4];
    #pragma unroll
    for (int mb = 0; mb < 2; ++mb)
        #pragma unroll
        for (int nb = 0; nb < 4; ++nb)
            #pragma unroll
            for (int r = 0; r < 16; ++r) acc[mb][nb][r] = 0.f;

    // ---- prologue: stage A(0) directly, DMA B(0) ----
    {
        float4 f0 = *(const float4*)(gA);
        float4 f1 = *(const float4*)(gA + 4);
        *(half8*)(Ab + adst) = cvt8(f0, f1);
        #pragma unroll
        for (int kcl = 0; kcl < 2; ++kcl)
            #pragma unroll
            for (int jbl = 0; jbl < 2; ++jbl) {
                const int jb = wave * 2 + jbl;
                GLD_LDS16(gB + ((size_t)jb * 32 + kcl) * 1024 + lane * 16,
                          Bb + (jb * 2 + kcl) * 1024 + lane * 16);
            }
    }
    __syncthreads();

    float4 R0, R1;   // A(ks+1) in flight

    for (int ks = 0; ks < NSTEPS; ++ks) {
        const int cur = ks & 1;
        const bool pf = (ks + 1 < NSTEPS);
        const char* Abc = Ab + cur * 8192;
        const char* Bbc = Bb + cur * 32768;

        // ---- issue-early: R <- A(ks+1); B-DMA(ks+1) -> other buffers ----
        if (pf) {
            const float* ga = gA + (ks + 1) * 32;
            R0 = *(const float4*)(ga);
            R1 = *(const float4*)(ga + 4);
            char* Bbn = Bb + (cur ^ 1) * 32768;
            #pragma unroll
            for (int kcl = 0; kcl < 2; ++kcl)
                #pragma unroll
                for (int jbl = 0; jbl < 2; ++jbl) {
                    const int jb = wave * 2 + jbl;
                    GLD_LDS16(gB + ((size_t)jb * 32 + (ks + 1) * 2 + kcl) * 1024 + lane * 16,
                              Bbn + (jb * 2 + kcl) * 1024 + lane * 16);
                }
        }
        __builtin_amdgcn_sched_barrier(0);

        // ---- compute: 2 kcl x (2 A-frags + 4 B-frags -> 8 MFMAs) ----
        #pragma unroll
        for (int kcl = 0; kcl < 2; ++kcl) {
            half8 a0 = *(const half8*)(Abc + ((wm * 2 + 0) * 2 + kcl) * 1024 + lane * 16);
            half8 a1 = *(const half8*)(Abc + ((wm * 2 + 1) * 2 + kcl) * 1024 + lane * 16);
            half8 b0 = *(const half8*)(Bbc + ((wn * 4 + 0) * 2 + kcl) * 1024 + lane * 16);
            half8 b1 = *(const half8*)(Bbc + ((wn * 4 + 1) * 2 + kcl) * 1024 + lane * 16);
            half8 b2 = *(const half8*)(Bbc + ((wn * 4 + 2) * 2 + kcl) * 1024 + lane * 16);
            half8 b3 = *(const half8*)(Bbc + ((wn * 4 + 3) * 2 + kcl) * 1024 + lane * 16);
            acc[0][0] = __builtin_amdgcn_mfma_f32_32x32x16_f16(a0, b0, acc[0][0], 0, 0, 0);
            acc[0][1] = __builtin_amdgcn_mfma_f32_32x32x16_f16(a0, b1, acc[0][1], 0, 0, 0);
            acc[0][2] = __builtin_amdgcn_mfma_f32_32x32x16_f16(a0, b2, acc[0][2], 0, 0, 0);
            acc[0][3] = __builtin_amdgcn_mfma_f32_32x32x16_f16(a0, b3, acc[0][3], 0, 0, 0);
            acc[1][0] = __builtin_amdgcn_mfma_f32_32x32x16_f16(a1, b0, acc[1][0], 0, 0, 0);
            acc[1][1] = __builtin_amdgcn_mfma_f32_32x32x16_f16(a1, b1, acc[1][1], 0, 0, 0);
            acc[1][2] = __builtin_amdgcn_mfma_f32_32x32x16_f16(a1, b2, acc[1][2], 0, 0, 0);
            acc[1][3] = __builtin_amdgcn_mfma_f32_32x32x16_f16(a1, b3, acc[1][3], 0, 0, 0);
        }
        __builtin_amdgcn_sched_barrier(0);

        // ---- write-late: R -> Ab[other] ----
        if (pf)
            *(half8*)(Ab + (cur ^ 1) * 8192 + adst) = cvt8(R0, R1);
        __syncthreads();
    }

    // ---- epilogue: relu + v-weight over this wave's 4 j-blocks, fold-tree per mb ----
    float bj[4], vj[4];
    #pragma unroll
    for (int nb = 0; nb < 4; ++nb) {
        const int j = (wn * 4 + nb) * 32 + l31;
        bj[nb] = bk[j];
        vj[nb] = v[j];
    }

    float* scr = (float*)lds;   // [4][128], aliases dead Ab (safe: after final barrier)

    float outv[2];
    int   outrow[2];
    #pragma unroll
    for (int mb = 0; mb < 2; ++mb) {
        float part[16];
        #pragma unroll
        for (int r = 0; r < 16; ++r) {
            float s = 0.f;
            #pragma unroll
            for (int nb = 0; nb < 4; ++nb)
                s += fmaxf(acc[mb][nb][r] + bj[nb], 0.f) * vj[nb];
            part[r] = s;
        }

        float q0[8];
        #pragma unroll
        for (int i = 0; i < 8; ++i) {
            const bool b = lane & 1;
            float keep = b ? part[i + 8] : part[i];
            float send = b ? part[i] : part[i + 8];
            q0[i] = keep + __shfl_xor(send, 1);
        }
        float q1[4];
        #pragma unroll
        for (int i = 0; i < 4; ++i) {
            const bool b = lane & 2;
            float keep = b ? q0[i + 4] : q0[i];
            float send = b ? q0[i] : q0[i + 4];
            q1[i] = keep + __shfl_xor(send, 2);
        }
        float q2[2];
        #pragma unroll
        for (int i = 0; i < 2; ++i) {
            const bool b = lane & 4;
            float keep = b ? q1[i + 2] : q1[i];
            float send = b ? q1[i] : q1[i + 2];
            q2[i] = keep + __shfl_xor(send, 4);
        }
        float q3;
        {
            const bool b = lane & 8;
            float keep = b ? q2[1] : q2[0];
            float send = b ? q2[0] : q2[1];
            q3 = keep + __shfl_xor(send, 8);
        }
        float s = q3 + __shfl_xor(q3, 16);
        const int rr  = ((l31 & 1) << 3) | ((l31 & 2) << 1) | ((l31 & 4) >> 1) | ((l31 & 8) >> 3);
        outrow[mb] = wm * 64 + mb * 32 + (rr & 3) + 8 * (rr >> 2) + 4 * lhi;
        outv[mb] = s;
    }
    #pragma unroll
    for (int mb = 0; mb < 2; ++mb)
        if (l31 < 16) scr[wn * 128 + outrow[mb]] = outv[mb];
    __syncthreads();

    if (tid < 128)
        logits[rowbase + tid] = scr[tid] + scr[128 + tid] + scr[256 + tid] + scr[384 + tid];
}

// ---------------- K3: per-block exp-sum over logits ----------------
__global__ void expsum_kernel(const float* __restrict__ logits, float* __restrict__ blocksum) {
    __shared__ float red[256];
    const int t = threadIdx.x;
    red[t] = expf(logits[blockIdx.x * 256 + t]);
    __syncthreads();
    for (int s = 128; s > 0; s >>= 1) {
        if (t < s) red[t] += red[t + s];
        __syncthreads();
    }
    if (t == 0) blocksum[blockIdx.x] = red[0];
}

// ---------------- K4: normalize ----------------
__global__ void norm_kernel(const float* __restrict__ logits, const float* __restrict__ blocksum,
                            float* __restrict__ out) {
    __shared__ float red[256];
    const int t = threadIdx.x;
    red[t] = blocksum[t];
    __syncthreads();
    for (int s = 128; s > 0; s >>= 1) {
        if (t < s) red[t] += red[t + s];
        __syncthreads();
    }
    const float zinv = 1.0f / red[0];
    const int i = blockIdx.x * 256 + t;
    out[i] = expf(logits[i]) * zinv;
}

extern "C" void kernel_launch(void* const* d_in, const int* in_sizes, int n_in,
                              void* d_out, int out_size, void* d_ws, size_t ws_size,
                              hipStream_t stream) {
    const float* Q    = (const float*)d_in[0];
    const float* Kmat = (const float*)d_in[1];
    const float* Wq   = (const float*)d_in[2];
    const float* bq   = (const float*)d_in[3];
    const float* Wk   = (const float*)d_in[4];
    const float* bk   = (const float*)d_in[5];
    const float* Wout = (const float*)d_in[6];
    float* out = (float*)d_out;

    char* ws = (char*)d_ws;
    _Float16* Wkf   = (_Float16*)(ws);                // 524288 B
    float* v        = (float*)(ws + 524288);          //   2048 B
    float* logits   = (float*)(ws + 526336);          // 262144 B
    float* blocksum = (float*)(ws + 788480);          //   1024 B

    hipLaunchKernelGGL(prep_kernel,   dim3(160),  dim3(256), 0, stream, Q, Wq, bq, Wout, Wk, v, Wkf);
    hipLaunchKernelGGL(score_kernel,  dim3(512),  dim3(512), 0, stream, Kmat, Wkf, bk, v, logits);
    hipLaunchKernelGGL(expsum_kernel, dim3(256),  dim3(256), 0, stream, logits, blocksum);
    hipLaunchKernelGGL(norm_kernel,   dim3(256),  dim3(256), 0, stream, logits, blocksum, out);
}